// Round 1
// baseline (1133.868 us; speedup 1.0000x reference)
//
#include <hip/hip_runtime.h>
#include <hip/hip_bf16.h>
#include <hip/hip_fp16.h>

#define TGT 2048
#define BSZ 4
#define EMB 1024
#define NH  16
#define HD  64
#define NTOK (TGT*BSZ)   // 8192
#define BH   (BSZ*NH)    // 64

typedef unsigned short u16;
typedef __attribute__((ext_vector_type(8))) short    s16x8;
typedef __attribute__((ext_vector_type(8))) _Float16 f16x8;
typedef __attribute__((ext_vector_type(2))) _Float16 f16x2;
typedef __attribute__((ext_vector_type(4))) float    f32x4;

#define MFMA_BF16(a,b,c) __builtin_amdgcn_mfma_f32_16x16x32_bf16(a,b,c,0,0,0)
#define MFMA_F16(a,b,c)  __builtin_amdgcn_mfma_f32_16x16x32_f16(a,b,c,0,0,0)

__device__ __forceinline__ void split_one(float x, u16& h, u16& l) {
  __hip_bfloat16 hb = __float2bfloat16(x);
  float hf = __bfloat162float(hb);
  __hip_bfloat16 lb = __float2bfloat16(x - hf);   // exact remainder, then rounded
  h = *reinterpret_cast<u16*>(&hb);
  l = *reinterpret_cast<u16*>(&lb);
}

// f32 -> (bf16 hi, bf16 lo), vectorized x4
__global__ __launch_bounds__(256) void split_kernel(const float* __restrict__ x,
    u16* __restrict__ hi, u16* __restrict__ lo, int n4) {
  int i = blockIdx.x * 256 + threadIdx.x;
  if (i >= n4) return;
  float4 v = reinterpret_cast<const float4*>(x)[i];
  ushort4 h, l;
  split_one(v.x, h.x, l.x);
  split_one(v.y, h.y, l.y);
  split_one(v.z, h.z, l.z);
  split_one(v.w, h.w, l.w);
  reinterpret_cast<ushort4*>(hi)[i] = h;
  reinterpret_cast<ushort4*>(lo)[i] = l;
}

// Split-bf16 NT GEMM: C[m][n] = sum_k (Ah+Al)[m][k]*(Bh+Bl)[n][k] (3-product Markidis).
// Tile 128x64, 4 waves (each 32 m-rows x 64 n), BK=32, LDS pitch 40 (pad vs bank conflicts).
// EPI: 0 = fp16 scatter (bh,t,d) with scale; 1 = fp16 scatter transposed (bh,d,s); 2 = f32 row-major.
template<int EPI>
__global__ __launch_bounds__(256) void gemm_split(
    const u16* __restrict__ Ah, const u16* __restrict__ Al,
    const u16* __restrict__ Bh, const u16* __restrict__ Bl,
    const float* __restrict__ bias, float scale, void* __restrict__ outp, int K)
{
  __shared__ __align__(16) u16 AhS[128][40];
  __shared__ __align__(16) u16 AlS[128][40];
  __shared__ __align__(16) u16 BhS[64][40];
  __shared__ __align__(16) u16 BlS[64][40];
  const int tid  = threadIdx.x;
  const int bm0  = blockIdx.y * 128;
  const int bn0  = blockIdx.x * 64;
  const int wave = tid >> 6, lane = tid & 63, lr = lane & 15, lg = lane >> 4;

  f32x4 zero = {0.f, 0.f, 0.f, 0.f};
  f32x4 acc[2][4];
  #pragma unroll
  for (int i = 0; i < 2; i++)
    #pragma unroll
    for (int j = 0; j < 4; j++) acc[i][j] = zero;

  for (int kt = 0; kt < K; kt += 32) {
    __syncthreads();
    #pragma unroll
    for (int i = 0; i < 2; i++) {
      int c = tid + i*256, r = c >> 2, co = (c & 3) * 8;
      *(uint4*)&AhS[r][co] = *(const uint4*)&Ah[(size_t)(bm0 + r)*K + kt + co];
      *(uint4*)&AlS[r][co] = *(const uint4*)&Al[(size_t)(bm0 + r)*K + kt + co];
    }
    {
      int r = tid >> 2, co = (tid & 3) * 8;
      *(uint4*)&BhS[r][co] = *(const uint4*)&Bh[(size_t)(bn0 + r)*K + kt + co];
      *(uint4*)&BlS[r][co] = *(const uint4*)&Bl[(size_t)(bn0 + r)*K + kt + co];
    }
    __syncthreads();
    s16x8 ah[2], al[2], bh[4], bl[4];
    #pragma unroll
    for (int mf = 0; mf < 2; mf++) {
      ah[mf] = *(const s16x8*)&AhS[wave*32 + mf*16 + lr][lg*8];
      al[mf] = *(const s16x8*)&AlS[wave*32 + mf*16 + lr][lg*8];
    }
    #pragma unroll
    for (int nf = 0; nf < 4; nf++) {
      bh[nf] = *(const s16x8*)&BhS[nf*16 + lr][lg*8];
      bl[nf] = *(const s16x8*)&BlS[nf*16 + lr][lg*8];
    }
    #pragma unroll
    for (int mf = 0; mf < 2; mf++)
      #pragma unroll
      for (int nf = 0; nf < 4; nf++) {
        acc[mf][nf] = MFMA_BF16(al[mf], bh[nf], acc[mf][nf]);
        acc[mf][nf] = MFMA_BF16(ah[mf], bl[nf], acc[mf][nf]);
        acc[mf][nf] = MFMA_BF16(ah[mf], bh[nf], acc[mf][nf]);
      }
  }
  // Epilogue. D layout (verified m89/m91): col = lane&15, row = (lane>>4)*4 + reg.
  #pragma unroll
  for (int mf = 0; mf < 2; mf++)
    #pragma unroll
    for (int nf = 0; nf < 4; nf++)
      #pragma unroll
      for (int r = 0; r < 4; r++) {
        int m = bm0 + wave*32 + mf*16 + lg*4 + r;
        int n = bn0 + nf*16 + lr;
        float v = (acc[mf][nf][r] + bias[n]) * scale;
        if constexpr (EPI == 0) {        // token m=(t,b), feature n=(h,d) -> (bh,t,d) fp16
          int t = m >> 2, b = m & 3, h = n >> 6, d = n & 63;
          ((_Float16*)outp)[(size_t)((b*NH + h)*TGT + t)*HD + d] = (_Float16)v;
        } else if constexpr (EPI == 1) { // V transposed: (bh,d,s) fp16
          int s = m >> 2, b = m & 3, h = n >> 6, d = n & 63;
          ((_Float16*)outp)[(size_t)((b*NH + h)*HD + d)*TGT + s] = (_Float16)v;
        } else {                         // f32 row-major (final output)
          ((float*)outp)[(size_t)m*EMB + n] = v;
        }
      }
}

// Flash attention per (bh, 64 t-rows): swapped QK^T (mfma(K,Q)) -> S[s][t] fragments,
// online softmax in exp2 units (scale folded into Q), PV via per-wave P LDS bounce.
// Emits O as split-bf16 in merged (token, e) layout + lse (log2 units).
__global__ __launch_bounds__(256) void flash_kernel(
    const _Float16* __restrict__ Qf, const _Float16* __restrict__ Kf,
    const _Float16* __restrict__ Vt, u16* __restrict__ Oh, u16* __restrict__ Ol,
    float* __restrict__ lse)
{
  __shared__ __align__(16) _Float16 Qs[64][72];
  __shared__ __align__(16) _Float16 Ks[64][72];
  __shared__ __align__(16) _Float16 Vs[64][72];      // [d][s]
  __shared__ __align__(16) _Float16 Ps[4][16][72];   // per-wave [t][s]
  const int tid = threadIdx.x, wave = tid >> 6, lane = tid & 63, lr = lane & 15, lg = lane >> 4;
  const int bh = blockIdx.y, t0 = blockIdx.x * 64;
  const int b = bh >> 4, h = bh & 15;

  #pragma unroll
  for (int i = 0; i < 2; i++) {
    int c = tid + i*256, r = c >> 3, co = (c & 7) * 8;
    *(uint4*)&Qs[r][co] = *(const uint4*)&Qf[((size_t)bh*TGT + t0 + r)*HD + co];
  }
  float m_run = -1e30f, l_run = 0.f;
  f32x4 zero = {0.f, 0.f, 0.f, 0.f};
  f32x4 accO[4];
  #pragma unroll
  for (int i = 0; i < 4; i++) accO[i] = zero;

  for (int s0 = 0; s0 < TGT; s0 += 64) {
    __syncthreads();
    #pragma unroll
    for (int i = 0; i < 2; i++) {
      int c = tid + i*256, r = c >> 3, co = (c & 7) * 8;
      *(uint4*)&Ks[r][co] = *(const uint4*)&Kf[((size_t)bh*TGT + s0 + r)*HD + co];
      *(uint4*)&Vs[r][co] = *(const uint4*)&Vt[((size_t)bh*HD + r)*TGT + s0 + co];
    }
    __syncthreads();
    f32x4 sacc[4];
    #pragma unroll
    for (int sf = 0; sf < 4; sf++) sacc[sf] = zero;
    #pragma unroll
    for (int sf = 0; sf < 4; sf++)
      #pragma unroll
      for (int kf = 0; kf < 2; kf++) {
        f16x8 a = *(const f16x8*)&Ks[sf*16 + lr][kf*32 + lg*8];
        f16x8 q = *(const f16x8*)&Qs[wave*16 + lr][kf*32 + lg*8];
        sacc[sf] = MFMA_F16(a, q, sacc[sf]);   // S[s=sf*16+lg*4+r][t=wave*16+lr]
      }
    float pm = -1e30f;
    #pragma unroll
    for (int sf = 0; sf < 4; sf++)
      #pragma unroll
      for (int r = 0; r < 4; r++) pm = fmaxf(pm, sacc[sf][r]);
    pm = fmaxf(pm, __shfl_xor(pm, 16, 64));
    pm = fmaxf(pm, __shfl_xor(pm, 32, 64));
    float m_new = fmaxf(m_run, pm);
    float fsc = exp2f(m_run - m_new);
    float psum = 0.f;
    #pragma unroll
    for (int sf = 0; sf < 4; sf++)
      #pragma unroll
      for (int r = 0; r < 4; r++) {
        float p = exp2f(sacc[sf][r] - m_new);
        sacc[sf][r] = p;
        psum += p;
      }
    psum += __shfl_xor(psum, 16, 64);
    psum += __shfl_xor(psum, 32, 64);
    l_run = l_run * fsc + psum;
    m_run = m_new;
    // P -> per-wave LDS (transposed to [t][s]); same-wave DS ordering makes this safe
    #pragma unroll
    for (int sf = 0; sf < 4; sf++) {
      f16x2 p01 = { (_Float16)sacc[sf][0], (_Float16)sacc[sf][1] };
      f16x2 p23 = { (_Float16)sacc[sf][2], (_Float16)sacc[sf][3] };
      *(f16x2*)&Ps[wave][lr][sf*16 + lg*4]     = p01;
      *(f16x2*)&Ps[wave][lr][sf*16 + lg*4 + 2] = p23;
    }
    float fr[4];
    #pragma unroll
    for (int r = 0; r < 4; r++) fr[r] = __shfl(fsc, lg*4 + r, 64);
    #pragma unroll
    for (int df = 0; df < 4; df++) {
      accO[df][0] *= fr[0]; accO[df][1] *= fr[1];
      accO[df][2] *= fr[2]; accO[df][3] *= fr[3];
    }
    f16x8 pa0 = *(const f16x8*)&Ps[wave][lr][lg*8];
    f16x8 pa1 = *(const f16x8*)&Ps[wave][lr][32 + lg*8];
    #pragma unroll
    for (int df = 0; df < 4; df++) {
      f16x8 v0 = *(const f16x8*)&Vs[df*16 + lr][lg*8];
      f16x8 v1 = *(const f16x8*)&Vs[df*16 + lr][32 + lg*8];
      accO[df] = MFMA_F16(pa0, v0, accO[df]);  // O[t=lg*4+r][d=df*16+lr]
      accO[df] = MFMA_F16(pa1, v1, accO[df]);
    }
  }
  float linv = 1.f / l_run;
  float rl[4];
  #pragma unroll
  for (int r = 0; r < 4; r++) rl[r] = __shfl(linv, lg*4 + r, 64);
  #pragma unroll
  for (int df = 0; df < 4; df++)
    #pragma unroll
    for (int r = 0; r < 4; r++) {
      float o = accO[df][r] * rl[r];
      int t = t0 + wave*16 + lg*4 + r;
      int d = df*16 + lr;
      size_t idx = (size_t)(t*BSZ + b)*EMB + h*HD + d;
      u16 hh, ll;
      split_one(o, hh, ll);
      Oh[idx] = hh; Ol[idx] = ll;
    }
  if (lane < 16)
    lse[(size_t)bh*TGT + t0 + wave*16 + lane] = m_run + log2f(l_run);
}

// avg_weights per (b, 32t, 32s): recompute scores for all 16 heads (4 heads/stage,
// wave w owns head hg*4+w), p = exp2(s - lse), LDS-reduce across waves, write once.
__global__ __launch_bounds__(256) void avg_kernel(
    const _Float16* __restrict__ Qf, const _Float16* __restrict__ Kf,
    const float* __restrict__ lse, float* __restrict__ avgO)
{
  __shared__ __align__(16) _Float16 Qs[4][32][72];
  __shared__ __align__(16) _Float16 Ks[4][32][72];
  __shared__ float pavg[32][33];
  __shared__ float lses[16][32];
  const int tid = threadIdx.x, wave = tid >> 6, lane = tid & 63, lr = lane & 15, lg = lane >> 4;
  const int s0 = blockIdx.x * 32, t0 = blockIdx.y * 32, b = blockIdx.z;

  for (int i = tid; i < 32*33; i += 256) (&pavg[0][0])[i] = 0.f;
  #pragma unroll
  for (int i = 0; i < 2; i++) {
    int c = tid + i*256, hh = c >> 5, tt = c & 31;
    lses[hh][tt] = lse[(size_t)(b*NH + hh)*TGT + t0 + tt];
  }
  f32x4 zero = {0.f, 0.f, 0.f, 0.f};
  f32x4 pacc[2][2];
  #pragma unroll
  for (int i = 0; i < 2; i++)
    #pragma unroll
    for (int j = 0; j < 2; j++) pacc[i][j] = zero;

  for (int hg = 0; hg < 4; hg++) {
    __syncthreads();
    #pragma unroll
    for (int i = 0; i < 4; i++) {
      int c = tid + i*256;
      int hd_ = c >> 8, r = (c >> 3) & 31, co = (c & 7) * 8;
      *(uint4*)&Qs[hd_][r][co] = *(const uint4*)&Qf[((size_t)(b*NH + hg*4 + hd_)*TGT + t0 + r)*HD + co];
      *(uint4*)&Ks[hd_][r][co] = *(const uint4*)&Kf[((size_t)(b*NH + hg*4 + hd_)*TGT + s0 + r)*HD + co];
    }
    __syncthreads();
    int habs = hg*4 + wave;
    #pragma unroll
    for (int mf = 0; mf < 2; mf++)
      #pragma unroll
      for (int nf = 0; nf < 2; nf++) {
        f32x4 a4 = zero;
        #pragma unroll
        for (int kf = 0; kf < 2; kf++) {
          f16x8 aq = *(const f16x8*)&Qs[wave][mf*16 + lr][kf*32 + lg*8];
          f16x8 bk = *(const f16x8*)&Ks[wave][nf*16 + lr][kf*32 + lg*8];
          a4 = MFMA_F16(aq, bk, a4);   // S[t=mf*16+lg*4+r][s=nf*16+lr]
        }
        #pragma unroll
        for (int r = 0; r < 4; r++) {
          float p = exp2f(a4[r] - lses[habs][mf*16 + lg*4 + r]);
          pacc[mf][nf][r] += p;
        }
      }
  }
  #pragma unroll
  for (int mf = 0; mf < 2; mf++)
    #pragma unroll
    for (int nf = 0; nf < 2; nf++)
      #pragma unroll
      for (int r = 0; r < 4; r++)
        atomicAdd(&pavg[mf*16 + lg*4 + r][nf*16 + lr], pacc[mf][nf][r]);
  __syncthreads();
  for (int i = tid; i < 32*32; i += 256) {
    int ti = i >> 5, sj = i & 31;
    avgO[((size_t)b*TGT + t0 + ti)*TGT + s0 + sj] = pavg[ti][sj] * (1.f/16.f);
  }
}

extern "C" void kernel_launch(void* const* d_in, const int* in_sizes, int n_in,
                              void* d_out, int out_size, void* d_ws, size_t ws_size,
                              hipStream_t stream) {
  const float* query = (const float*)d_in[0];
  const float* key_  = (const float*)d_in[1];
  const float* value = (const float*)d_in[2];
  const float* ipw   = (const float*)d_in[3];  // (3072,1024)
  const float* ipb   = (const float*)d_in[4];  // (3072,)
  const float* opw   = (const float*)d_in[5];  // (1024,1024)
  const float* opb   = (const float*)d_in[6];  // (1024,)
  float* out = (float*)d_out;
  float* avg = out + (size_t)TGT*BSZ*EMB;

  char* ws = (char*)d_ws;
  size_t o = 0;
  auto alloc = [&](size_t bytes) { char* p = ws + o; o += bytes; return p; };
  u16* Wh  = (u16*)alloc((size_t)3*EMB*EMB*2);
  u16* Wl  = (u16*)alloc((size_t)3*EMB*EMB*2);
  u16* Woh = (u16*)alloc((size_t)EMB*EMB*2);
  u16* Wol = (u16*)alloc((size_t)EMB*EMB*2);
  u16* Xh  = (u16*)alloc((size_t)NTOK*EMB*2);
  u16* Xl  = (u16*)alloc((size_t)NTOK*EMB*2);
  _Float16* Qf = (_Float16*)alloc((size_t)NTOK*EMB*2);
  _Float16* Kf = (_Float16*)alloc((size_t)NTOK*EMB*2);
  _Float16* Vt = (_Float16*)alloc((size_t)NTOK*EMB*2);
  u16* OhA = (u16*)alloc((size_t)NTOK*EMB*2);
  u16* OlA = (u16*)alloc((size_t)NTOK*EMB*2);
  float* lseA = (float*)alloc((size_t)BH*TGT*4);
  (void)ws_size; (void)in_sizes; (void)n_in; (void)out_size;
  // total ws use: ~128.5 MiB

  const float QSCALE = 0.18033688011112042f;  // log2(e)/8 -> exp2-unit scores

  split_kernel<<<3*EMB*EMB/1024, 256, 0, stream>>>(ipw, Wh, Wl, 3*EMB*EMB/4);
  split_kernel<<<EMB*EMB/1024, 256, 0, stream>>>(opw, Woh, Wol, EMB*EMB/4);

  dim3 ggrid(EMB/64, NTOK/128);
  split_kernel<<<NTOK*EMB/1024, 256, 0, stream>>>(query, Xh, Xl, NTOK*EMB/4);
  gemm_split<0><<<ggrid, 256, 0, stream>>>(Xh, Xl, Wh, Wl, ipb, QSCALE, (void*)Qf, EMB);
  split_kernel<<<NTOK*EMB/1024, 256, 0, stream>>>(key_, Xh, Xl, NTOK*EMB/4);
  gemm_split<0><<<ggrid, 256, 0, stream>>>(Xh, Xl, Wh + (size_t)EMB*EMB, Wl + (size_t)EMB*EMB,
                                           ipb + EMB, 1.0f, (void*)Kf, EMB);
  split_kernel<<<NTOK*EMB/1024, 256, 0, stream>>>(value, Xh, Xl, NTOK*EMB/4);
  gemm_split<1><<<ggrid, 256, 0, stream>>>(Xh, Xl, Wh + (size_t)2*EMB*EMB, Wl + (size_t)2*EMB*EMB,
                                           ipb + 2*EMB, 1.0f, (void*)Vt, EMB);

  flash_kernel<<<dim3(TGT/64, BH), 256, 0, stream>>>(Qf, Kf, Vt, OhA, OlA, lseA);
  avg_kernel<<<dim3(TGT/32, TGT/32, BSZ), 256, 0, stream>>>(Qf, Kf, lseA, avg);
  gemm_split<2><<<ggrid, 256, 0, stream>>>(OhA, OlA, Woh, Wol, opb, 1.0f, (void*)out, EMB);
}

// Round 2
// 778.144 us; speedup vs baseline: 1.4571x; 1.4571x over previous
//
#include <hip/hip_runtime.h>
#include <hip/hip_bf16.h>
#include <hip/hip_fp16.h>

#define TGT 2048
#define BSZ 4
#define EMB 1024
#define NH  16
#define HD  64
#define NTOK (TGT*BSZ)   // 8192
#define BH   (BSZ*NH)    // 64

typedef unsigned short u16;
typedef __attribute__((ext_vector_type(8))) short    s16x8;
typedef __attribute__((ext_vector_type(8))) _Float16 f16x8;
typedef __attribute__((ext_vector_type(2))) _Float16 f16x2;
typedef __attribute__((ext_vector_type(4))) float    f32x4;

#define MFMA_BF16(a,b,c) __builtin_amdgcn_mfma_f32_16x16x32_bf16(a,b,c,0,0,0)
#define MFMA_F16(a,b,c)  __builtin_amdgcn_mfma_f32_16x16x32_f16(a,b,c,0,0,0)

// async global->LDS, 16B per lane; LDS dest = uniform base + lane*16
#define GLOAD_LDS16(gsrc, ldst) \
  __builtin_amdgcn_global_load_lds((const __attribute__((address_space(1))) unsigned int*)(gsrc), \
                                   (__attribute__((address_space(3))) unsigned int*)(ldst), 16, 0, 0)

__device__ __forceinline__ void split_one(float x, u16& h, u16& l) {
  __hip_bfloat16 hb = __float2bfloat16(x);
  float hf = __bfloat162float(hb);
  __hip_bfloat16 lb = __float2bfloat16(x - hf);   // exact remainder, then rounded
  h = *reinterpret_cast<u16*>(&hb);
  l = *reinterpret_cast<u16*>(&lb);
}

// f32 -> (bf16 hi, bf16 lo), vectorized x4
__global__ __launch_bounds__(256) void split_kernel(const float* __restrict__ x,
    u16* __restrict__ hi, u16* __restrict__ lo, int n4) {
  int i = blockIdx.x * 256 + threadIdx.x;
  if (i >= n4) return;
  float4 v = reinterpret_cast<const float4*>(x)[i];
  ushort4 h, l;
  split_one(v.x, h.x, l.x);
  split_one(v.y, h.y, l.y);
  split_one(v.z, h.z, l.z);
  split_one(v.w, h.w, l.w);
  reinterpret_cast<ushort4*>(hi)[i] = h;
  reinterpret_cast<ushort4*>(lo)[i] = l;
}

// Split-bf16 NT GEMM: C[m][n] = sum_k (Ah+Al)[m][k]*(Bh+Bl)[n][k] (3-product Markidis).
// Tile 128x64, 4 waves (each 32 m-rows x 64 n), BK=32, LDS pitch 40 (pad vs bank conflicts).
// EPI: 0 = fp16 scatter (bh,t,d) with scale; 1 = fp16 scatter transposed (bh,d,s); 2 = f32 row-major.
template<int EPI>
__global__ __launch_bounds__(256) void gemm_split(
    const u16* __restrict__ Ah, const u16* __restrict__ Al,
    const u16* __restrict__ Bh, const u16* __restrict__ Bl,
    const float* __restrict__ bias, float scale, void* __restrict__ outp, int K)
{
  __shared__ __align__(16) u16 AhS[128][40];
  __shared__ __align__(16) u16 AlS[128][40];
  __shared__ __align__(16) u16 BhS[64][40];
  __shared__ __align__(16) u16 BlS[64][40];
  const int tid  = threadIdx.x;
  const int bm0  = blockIdx.y * 128;
  const int bn0  = blockIdx.x * 64;
  const int wave = tid >> 6, lane = tid & 63, lr = lane & 15, lg = lane >> 4;

  f32x4 zero = {0.f, 0.f, 0.f, 0.f};
  f32x4 acc[2][4];
  #pragma unroll
  for (int i = 0; i < 2; i++)
    #pragma unroll
    for (int j = 0; j < 4; j++) acc[i][j] = zero;

  for (int kt = 0; kt < K; kt += 32) {
    __syncthreads();
    #pragma unroll
    for (int i = 0; i < 2; i++) {
      int c = tid + i*256, r = c >> 2, co = (c & 3) * 8;
      *(uint4*)&AhS[r][co] = *(const uint4*)&Ah[(size_t)(bm0 + r)*K + kt + co];
      *(uint4*)&AlS[r][co] = *(const uint4*)&Al[(size_t)(bm0 + r)*K + kt + co];
    }
    {
      int r = tid >> 2, co = (tid & 3) * 8;
      *(uint4*)&BhS[r][co] = *(const uint4*)&Bh[(size_t)(bn0 + r)*K + kt + co];
      *(uint4*)&BlS[r][co] = *(const uint4*)&Bl[(size_t)(bn0 + r)*K + kt + co];
    }
    __syncthreads();
    s16x8 ah[2], al[2], bh[4], bl[4];
    #pragma unroll
    for (int mf = 0; mf < 2; mf++) {
      ah[mf] = *(const s16x8*)&AhS[wave*32 + mf*16 + lr][lg*8];
      al[mf] = *(const s16x8*)&AlS[wave*32 + mf*16 + lr][lg*8];
    }
    #pragma unroll
    for (int nf = 0; nf < 4; nf++) {
      bh[nf] = *(const s16x8*)&BhS[nf*16 + lr][lg*8];
      bl[nf] = *(const s16x8*)&BlS[nf*16 + lr][lg*8];
    }
    #pragma unroll
    for (int mf = 0; mf < 2; mf++)
      #pragma unroll
      for (int nf = 0; nf < 4; nf++) {
        acc[mf][nf] = MFMA_BF16(al[mf], bh[nf], acc[mf][nf]);
        acc[mf][nf] = MFMA_BF16(ah[mf], bl[nf], acc[mf][nf]);
        acc[mf][nf] = MFMA_BF16(ah[mf], bh[nf], acc[mf][nf]);
      }
  }
  // Epilogue. D layout (verified m89/m91): col = lane&15, row = (lane>>4)*4 + reg.
  #pragma unroll
  for (int mf = 0; mf < 2; mf++)
    #pragma unroll
    for (int nf = 0; nf < 4; nf++)
      #pragma unroll
      for (int r = 0; r < 4; r++) {
        int m = bm0 + wave*32 + mf*16 + lg*4 + r;
        int n = bn0 + nf*16 + lr;
        float v = (acc[mf][nf][r] + bias[n]) * scale;
        if constexpr (EPI == 0) {        // token m=(t,b), feature n=(h,d) -> (bh,t,d) fp16
          int t = m >> 2, b = m & 3, h = n >> 6, d = n & 63;
          ((_Float16*)outp)[(size_t)((b*NH + h)*TGT + t)*HD + d] = (_Float16)v;
        } else if constexpr (EPI == 1) { // V transposed: (bh,d,s) fp16
          int s = m >> 2, b = m & 3, h = n >> 6, d = n & 63;
          ((_Float16*)outp)[(size_t)((b*NH + h)*HD + d)*TGT + s] = (_Float16)v;
        } else {                         // f32 row-major (final output)
          ((float*)outp)[(size_t)m*EMB + n] = v;
        }
      }
}

// Flash attention per (bh, 64 t-rows): swapped QK^T (mfma(K,Q)) -> S[s][t] fragments,
// online softmax in exp2 units (scale folded into Q), PV via per-wave P LDS bounce.
// Emits O as split-bf16 in merged (token, e) layout + lse (log2 units).
__global__ __launch_bounds__(256) void flash_kernel(
    const _Float16* __restrict__ Qf, const _Float16* __restrict__ Kf,
    const _Float16* __restrict__ Vt, u16* __restrict__ Oh, u16* __restrict__ Ol,
    float* __restrict__ lse)
{
  __shared__ __align__(16) _Float16 Qs[64][72];
  __shared__ __align__(16) _Float16 Ks[64][72];
  __shared__ __align__(16) _Float16 Vs[64][72];      // [d][s]
  __shared__ __align__(16) _Float16 Ps[4][16][72];   // per-wave [t][s]
  const int tid = threadIdx.x, wave = tid >> 6, lane = tid & 63, lr = lane & 15, lg = lane >> 4;
  const int bh = blockIdx.y, t0 = blockIdx.x * 64;
  const int b = bh >> 4, h = bh & 15;

  #pragma unroll
  for (int i = 0; i < 2; i++) {
    int c = tid + i*256, r = c >> 3, co = (c & 7) * 8;
    *(uint4*)&Qs[r][co] = *(const uint4*)&Qf[((size_t)bh*TGT + t0 + r)*HD + co];
  }
  float m_run = -1e30f, l_run = 0.f;
  f32x4 zero = {0.f, 0.f, 0.f, 0.f};
  f32x4 accO[4];
  #pragma unroll
  for (int i = 0; i < 4; i++) accO[i] = zero;

  for (int s0 = 0; s0 < TGT; s0 += 64) {
    __syncthreads();
    #pragma unroll
    for (int i = 0; i < 2; i++) {
      int c = tid + i*256, r = c >> 3, co = (c & 7) * 8;
      *(uint4*)&Ks[r][co] = *(const uint4*)&Kf[((size_t)bh*TGT + s0 + r)*HD + co];
      *(uint4*)&Vs[r][co] = *(const uint4*)&Vt[((size_t)bh*HD + r)*TGT + s0 + co];
    }
    __syncthreads();
    f32x4 sacc[4];
    #pragma unroll
    for (int sf = 0; sf < 4; sf++) sacc[sf] = zero;
    #pragma unroll
    for (int sf = 0; sf < 4; sf++)
      #pragma unroll
      for (int kf = 0; kf < 2; kf++) {
        f16x8 a = *(const f16x8*)&Ks[sf*16 + lr][kf*32 + lg*8];
        f16x8 q = *(const f16x8*)&Qs[wave*16 + lr][kf*32 + lg*8];
        sacc[sf] = MFMA_F16(a, q, sacc[sf]);   // S[s=sf*16+lg*4+r][t=wave*16+lr]
      }
    float pm = -1e30f;
    #pragma unroll
    for (int sf = 0; sf < 4; sf++)
      #pragma unroll
      for (int r = 0; r < 4; r++) pm = fmaxf(pm, sacc[sf][r]);
    pm = fmaxf(pm, __shfl_xor(pm, 16, 64));
    pm = fmaxf(pm, __shfl_xor(pm, 32, 64));
    float m_new = fmaxf(m_run, pm);
    float fsc = exp2f(m_run - m_new);
    float psum = 0.f;
    #pragma unroll
    for (int sf = 0; sf < 4; sf++)
      #pragma unroll
      for (int r = 0; r < 4; r++) {
        float p = exp2f(sacc[sf][r] - m_new);
        sacc[sf][r] = p;
        psum += p;
      }
    psum += __shfl_xor(psum, 16, 64);
    psum += __shfl_xor(psum, 32, 64);
    l_run = l_run * fsc + psum;
    m_run = m_new;
    // P -> per-wave LDS (transposed to [t][s]); same-wave DS ordering makes this safe
    #pragma unroll
    for (int sf = 0; sf < 4; sf++) {
      f16x2 p01 = { (_Float16)sacc[sf][0], (_Float16)sacc[sf][1] };
      f16x2 p23 = { (_Float16)sacc[sf][2], (_Float16)sacc[sf][3] };
      *(f16x2*)&Ps[wave][lr][sf*16 + lg*4]     = p01;
      *(f16x2*)&Ps[wave][lr][sf*16 + lg*4 + 2] = p23;
    }
    float fr[4];
    #pragma unroll
    for (int r = 0; r < 4; r++) fr[r] = __shfl(fsc, lg*4 + r, 64);
    #pragma unroll
    for (int df = 0; df < 4; df++) {
      accO[df][0] *= fr[0]; accO[df][1] *= fr[1];
      accO[df][2] *= fr[2]; accO[df][3] *= fr[3];
    }
    f16x8 pa0 = *(const f16x8*)&Ps[wave][lr][lg*8];
    f16x8 pa1 = *(const f16x8*)&Ps[wave][lr][32 + lg*8];
    #pragma unroll
    for (int df = 0; df < 4; df++) {
      f16x8 v0 = *(const f16x8*)&Vs[df*16 + lr][lg*8];
      f16x8 v1 = *(const f16x8*)&Vs[df*16 + lr][32 + lg*8];
      accO[df] = MFMA_F16(pa0, v0, accO[df]);  // O[t=lg*4+r][d=df*16+lr]
      accO[df] = MFMA_F16(pa1, v1, accO[df]);
    }
  }
  float linv = 1.f / l_run;
  float rl[4];
  #pragma unroll
  for (int r = 0; r < 4; r++) rl[r] = __shfl(linv, lg*4 + r, 64);
  #pragma unroll
  for (int df = 0; df < 4; df++)
    #pragma unroll
    for (int r = 0; r < 4; r++) {
      float o = accO[df][r] * rl[r];
      int t = t0 + wave*16 + lg*4 + r;
      int d = df*16 + lr;
      size_t idx = (size_t)(t*BSZ + b)*EMB + h*HD + d;
      u16 hh, ll;
      split_one(o, hh, ll);
      Oh[idx] = hh; Ol[idx] = ll;
    }
  if (lane < 16)
    lse[(size_t)bh*TGT + t0 + wave*16 + lane] = m_run + log2f(l_run);
}

// avg_weights v2: one block per (b, 128t x 128s) tile; loop all 16 heads with
// global_load_lds staging (XOR-swizzled source so ds_read_b128 is conflict-free),
// accumulate p = exp2(S - lse) in registers, single direct global write.
__global__ __launch_bounds__(256) void avg_kernel(
    const _Float16* __restrict__ Qf, const _Float16* __restrict__ Kf,
    const float* __restrict__ lse, float* __restrict__ avgO)
{
  __shared__ __align__(16) _Float16 Qs[128][64];   // 16 KB, 128B rows, XOR-swizzled granules
  __shared__ __align__(16) _Float16 Ks[128][64];   // 16 KB
  __shared__ float lses[NH][128];                  // 8 KB
  const int tid = threadIdx.x, wave = tid >> 6, lane = tid & 63, lr = lane & 15, lg = lane >> 4;

  // XCD-chunked swizzle over 1024 blocks (1024 % 8 == 0 -> bijective)
  int fid = blockIdx.x;
  int nid = (fid & 7) * 128 + (fid >> 3);
  int st = nid & 15, tt = (nid >> 4) & 15, b = nid >> 8;
  int s0 = st * 128, t0 = tt * 128;

  // stage lse for all heads, this block's 128 t-rows
  #pragma unroll
  for (int i = 0; i < 8; i++) {
    int idx = tid + i * 256;               // 2048 = 16*128
    int hh = idx >> 7, t = idx & 127;
    lses[hh][t] = lse[(size_t)(b*NH + hh)*TGT + t0 + t];
  }

  f32x4 zero = {0.f, 0.f, 0.f, 0.f};
  f32x4 acc[2][8];
  #pragma unroll
  for (int i = 0; i < 2; i++)
    #pragma unroll
    for (int j = 0; j < 8; j++) acc[i][j] = zero;

  const int rQ = wave * 32;
  // per-lane source swizzle offset within a 1KB staging chunk:
  // LDS slot (row = J*8 + l>>3, granule = l&7) gets global granule (l&7)^(l>>3)
  const int srcsub = (((lane & 7) ^ (lane >> 3)) << 4) + (lane >> 3) * 128;

  for (int h = 0; h < NH; h++) {
    __syncthreads();   // protect LDS from previous head's readers
    {
      const char* qb = (const char*)(Qf + ((size_t)(b*NH + h)*TGT + t0) * HD);
      const char* kb = (const char*)(Kf + ((size_t)(b*NH + h)*TGT + s0) * HD);
      const char* gb = (wave < 2) ? qb : kb;
      char* lb = (char*)((wave < 2) ? &Qs[0][0] : &Ks[0][0]);
      const int half = (wave & 1) * 8;
      #pragma unroll
      for (int j = 0; j < 8; j++) {
        int J = half + j;
        GLOAD_LDS16(gb + (size_t)J * 1024 + srcsub, lb + J * 1024);
      }
    }
    __syncthreads();   // drains vmcnt -> staged data visible

    // hoist this head's lse values (one per output row this lane owns)
    float lsr[2][4];
    #pragma unroll
    for (int mf = 0; mf < 2; mf++)
      #pragma unroll
      for (int r = 0; r < 4; r++)
        lsr[mf][r] = lses[h][rQ + mf*16 + lg*4 + r];

    // Q fragments (swizzled read)
    f16x8 aq[2][2];
    #pragma unroll
    for (int mf = 0; mf < 2; mf++)
      #pragma unroll
      for (int kf = 0; kf < 2; kf++) {
        int row = rQ + mf*16 + lr;
        int cb = ((kf*4 + lg) ^ (row & 7)) << 4;
        aq[mf][kf] = *(const f16x8*)((const char*)&Qs[0][0] + row*128 + cb);
      }
    #pragma unroll
    for (int nf = 0; nf < 8; nf++) {
      f32x4 s4[2] = {zero, zero};
      #pragma unroll
      for (int kf = 0; kf < 2; kf++) {
        int row = nf*16 + lr;
        int cb = ((kf*4 + lg) ^ (row & 7)) << 4;
        f16x8 bk = *(const f16x8*)((const char*)&Ks[0][0] + row*128 + cb);
        s4[0] = MFMA_F16(aq[0][kf], bk, s4[0]);  // S[t=rQ+mf*16+lg*4+r][s=nf*16+lr]
        s4[1] = MFMA_F16(aq[1][kf], bk, s4[1]);
      }
      #pragma unroll
      for (int mf = 0; mf < 2; mf++)
        #pragma unroll
        for (int r = 0; r < 4; r++)
          acc[mf][nf][r] += exp2f(s4[mf][r] - lsr[mf][r]);
    }
  }

  // direct global write, /16
  #pragma unroll
  for (int mf = 0; mf < 2; mf++)
    #pragma unroll
    for (int nf = 0; nf < 8; nf++)
      #pragma unroll
      for (int r = 0; r < 4; r++) {
        int t = t0 + rQ + mf*16 + lg*4 + r;
        int s = s0 + nf*16 + lr;
        avgO[((size_t)b*TGT + t)*TGT + s] = acc[mf][nf][r] * (1.f/16.f);
      }
}

extern "C" void kernel_launch(void* const* d_in, const int* in_sizes, int n_in,
                              void* d_out, int out_size, void* d_ws, size_t ws_size,
                              hipStream_t stream) {
  const float* query = (const float*)d_in[0];
  const float* key_  = (const float*)d_in[1];
  const float* value = (const float*)d_in[2];
  const float* ipw   = (const float*)d_in[3];  // (3072,1024)
  const float* ipb   = (const float*)d_in[4];  // (3072,)
  const float* opw   = (const float*)d_in[5];  // (1024,1024)
  const float* opb   = (const float*)d_in[6];  // (1024,)
  float* out = (float*)d_out;
  float* avg = out + (size_t)TGT*BSZ*EMB;

  char* ws = (char*)d_ws;
  size_t o = 0;
  auto alloc = [&](size_t bytes) { char* p = ws + o; o += bytes; return p; };
  u16* Wh  = (u16*)alloc((size_t)3*EMB*EMB*2);
  u16* Wl  = (u16*)alloc((size_t)3*EMB*EMB*2);
  u16* Woh = (u16*)alloc((size_t)EMB*EMB*2);
  u16* Wol = (u16*)alloc((size_t)EMB*EMB*2);
  u16* Xh  = (u16*)alloc((size_t)NTOK*EMB*2);
  u16* Xl  = (u16*)alloc((size_t)NTOK*EMB*2);
  _Float16* Qf = (_Float16*)alloc((size_t)NTOK*EMB*2);
  _Float16* Kf = (_Float16*)alloc((size_t)NTOK*EMB*2);
  _Float16* Vt = (_Float16*)alloc((size_t)NTOK*EMB*2);
  u16* OhA = (u16*)alloc((size_t)NTOK*EMB*2);
  u16* OlA = (u16*)alloc((size_t)NTOK*EMB*2);
  float* lseA = (float*)alloc((size_t)BH*TGT*4);
  (void)ws_size; (void)in_sizes; (void)n_in; (void)out_size;
  // total ws use: ~128.5 MiB

  const float QSCALE = 0.18033688011112042f;  // log2(e)/8 -> exp2-unit scores

  split_kernel<<<3*EMB*EMB/1024, 256, 0, stream>>>(ipw, Wh, Wl, 3*EMB*EMB/4);
  split_kernel<<<EMB*EMB/1024, 256, 0, stream>>>(opw, Woh, Wol, EMB*EMB/4);

  dim3 ggrid(EMB/64, NTOK/128);
  split_kernel<<<NTOK*EMB/1024, 256, 0, stream>>>(query, Xh, Xl, NTOK*EMB/4);
  gemm_split<0><<<ggrid, 256, 0, stream>>>(Xh, Xl, Wh, Wl, ipb, QSCALE, (void*)Qf, EMB);
  split_kernel<<<NTOK*EMB/1024, 256, 0, stream>>>(key_, Xh, Xl, NTOK*EMB/4);
  gemm_split<0><<<ggrid, 256, 0, stream>>>(Xh, Xl, Wh + (size_t)EMB*EMB, Wl + (size_t)EMB*EMB,
                                           ipb + EMB, 1.0f, (void*)Kf, EMB);
  split_kernel<<<NTOK*EMB/1024, 256, 0, stream>>>(value, Xh, Xl, NTOK*EMB/4);
  gemm_split<1><<<ggrid, 256, 0, stream>>>(Xh, Xl, Wh + (size_t)2*EMB*EMB, Wl + (size_t)2*EMB*EMB,
                                           ipb + 2*EMB, 1.0f, (void*)Vt, EMB);

  flash_kernel<<<dim3(TGT/64, BH), 256, 0, stream>>>(Qf, Kf, Vt, OhA, OlA, lseA);
  avg_kernel<<<1024, 256, 0, stream>>>(Qf, Kf, lseA, avg);
  gemm_split<2><<<ggrid, 256, 0, stream>>>(OhA, OlA, Woh, Wol, opb, 1.0f, (void*)out, EMB);
}

// Round 3
// 713.991 us; speedup vs baseline: 1.5881x; 1.0899x over previous
//
#include <hip/hip_runtime.h>
#include <hip/hip_bf16.h>
#include <hip/hip_fp16.h>

#define TGT 2048
#define BSZ 4
#define EMB 1024
#define NH  16
#define HD  64
#define NTOK (TGT*BSZ)   // 8192
#define BH   (BSZ*NH)    // 64

typedef unsigned short u16;
typedef __attribute__((ext_vector_type(8))) short    s16x8;
typedef __attribute__((ext_vector_type(8))) _Float16 f16x8;
typedef __attribute__((ext_vector_type(2))) _Float16 f16x2;
typedef __attribute__((ext_vector_type(4))) float    f32x4;

#define MFMA_BF16(a,b,c) __builtin_amdgcn_mfma_f32_16x16x32_bf16(a,b,c,0,0,0)
#define MFMA_F16(a,b,c)  __builtin_amdgcn_mfma_f32_16x16x32_f16(a,b,c,0,0,0)

// async global->LDS, 16B per lane; LDS dest = wave-uniform base + lane*16
#define GLOAD_LDS16(gsrc, ldst) \
  __builtin_amdgcn_global_load_lds((const __attribute__((address_space(1))) unsigned int*)(gsrc), \
                                   (__attribute__((address_space(3))) unsigned int*)(ldst), 16, 0, 0)

__device__ __forceinline__ void split_one(float x, u16& h, u16& l) {
  __hip_bfloat16 hb = __float2bfloat16(x);
  float hf = __bfloat162float(hb);
  __hip_bfloat16 lb = __float2bfloat16(x - hf);   // exact remainder, then rounded
  h = *reinterpret_cast<u16*>(&hb);
  l = *reinterpret_cast<u16*>(&lb);
}

// f32 -> (bf16 hi, bf16 lo), vectorized x4
__global__ __launch_bounds__(256) void split_kernel(const float* __restrict__ x,
    u16* __restrict__ hi, u16* __restrict__ lo, int n4) {
  int i = blockIdx.x * 256 + threadIdx.x;
  if (i >= n4) return;
  float4 v = reinterpret_cast<const float4*>(x)[i];
  ushort4 h, l;
  split_one(v.x, h.x, l.x);
  split_one(v.y, h.y, l.y);
  split_one(v.z, h.z, l.z);
  split_one(v.w, h.w, l.w);
  reinterpret_cast<ushort4*>(hi)[i] = h;
  reinterpret_cast<ushort4*>(lo)[i] = l;
}

// Split-bf16 NT GEMM v2 (m97-style): C[m][n] = sum_k (Ah+Al)[m][k]*(Bh+Bl)[n][k],
// 3-product Markidis. BM=BN=128, BK=32, 4 waves (each 32m x 128n, acc 2x8 f32x4).
// LDS tiles [128 rows][128B]: granules g0-3 = hi k-halves, g4-7 = lo; stored granule
// XOR-swizzled by (row&7) so ds_read_b128 fragment reads are conflict-free (m214 +89% fix).
// Staged via global_load_lds w=16 with pre-swizzled per-lane SOURCE (m173 pattern).
// EPI: 0 = fp16 scatter (bh,t,d) with scale; 1 = fp16 scatter transposed (bh,d,s); 2 = f32 row-major.
template<int EPI>
__global__ __launch_bounds__(256) void gemm_split(
    const u16* __restrict__ Ah, const u16* __restrict__ Al,
    const u16* __restrict__ Bh, const u16* __restrict__ Bl,
    const float* __restrict__ bias, float scale, void* __restrict__ outp, int K)
{
  __shared__ __align__(16) u16 As[128*64];   // 16 KB
  __shared__ __align__(16) u16 Bs[128*64];   // 16 KB
  const int tid  = threadIdx.x;
  const int bm0  = blockIdx.y * 128;
  const int bn0  = blockIdx.x * 128;
  const int wave = tid >> 6, lane = tid & 63, lr = lane & 15, lg = lane >> 4;

  f32x4 zero = {0.f, 0.f, 0.f, 0.f};
  f32x4 acc[2][8];
  #pragma unroll
  for (int i = 0; i < 2; i++)
    #pragma unroll
    for (int j = 0; j < 8; j++) acc[i][j] = zero;

  // Staging jobs: granule gi = tid + j*256 (j=0..3) covers the 1024 granules of one
  // 16 KB tile. gi -> (row = gi>>3, stored granule = gi&7). The source granule is
  // stored^(row&7); granules 0-3 come from the hi matrix, 4-7 from lo.
  const u16* srcA[4];
  const u16* srcB[4];
  #pragma unroll
  for (int j = 0; j < 4; j++) {
    int gi  = tid + j*256;
    int row = gi >> 3;
    int lgc = (gi & 7) ^ (row & 7);
    const u16* baA = (lgc < 4) ? Ah : Al;
    const u16* baB = (lgc < 4) ? Bh : Bl;
    srcA[j] = baA + (size_t)(bm0 + row)*K + (lgc & 3)*8;
    srcB[j] = baB + (size_t)(bn0 + row)*K + (lgc & 3)*8;
  }
  char* AsB = (char*)As;
  char* BsB = (char*)Bs;
  const int ldsb = wave*1024;   // wave-uniform chunk base

  for (int kt = 0; kt < K; kt += 32) {
    __syncthreads();
    #pragma unroll
    for (int j = 0; j < 4; j++) {
      GLOAD_LDS16(srcA[j] + kt, AsB + ldsb + j*4096);
      GLOAD_LDS16(srcB[j] + kt, BsB + ldsb + j*4096);
    }
    __syncthreads();   // drains vmcnt -> staged tiles visible

    s16x8 ah[2], al2[2];
    #pragma unroll
    for (int mf = 0; mf < 2; mf++) {
      int row = wave*32 + mf*16 + lr;
      const char* rb = AsB + row*128;
      ah[mf]  = *(const s16x8*)(rb + (((lg    ) ^ (row & 7)) << 4));
      al2[mf] = *(const s16x8*)(rb + (((lg | 4) ^ (row & 7)) << 4));
    }
    #pragma unroll
    for (int nf = 0; nf < 8; nf++) {
      int row = nf*16 + lr;
      const char* rb = BsB + row*128;
      s16x8 bh8 = *(const s16x8*)(rb + (((lg    ) ^ (row & 7)) << 4));
      s16x8 bl8 = *(const s16x8*)(rb + (((lg | 4) ^ (row & 7)) << 4));
      #pragma unroll
      for (int mf = 0; mf < 2; mf++) {
        acc[mf][nf] = MFMA_BF16(al2[mf], bh8, acc[mf][nf]);
        acc[mf][nf] = MFMA_BF16(ah[mf],  bl8, acc[mf][nf]);
        acc[mf][nf] = MFMA_BF16(ah[mf],  bh8, acc[mf][nf]);
      }
    }
  }
  // Epilogue. D layout (verified m89/m91): col = lane&15, row = (lane>>4)*4 + reg.
  #pragma unroll
  for (int mf = 0; mf < 2; mf++)
    #pragma unroll
    for (int nf = 0; nf < 8; nf++)
      #pragma unroll
      for (int r = 0; r < 4; r++) {
        int m = bm0 + wave*32 + mf*16 + lg*4 + r;
        int n = bn0 + nf*16 + lr;
        float v = (acc[mf][nf][r] + bias[n]) * scale;
        if constexpr (EPI == 0) {        // token m=(t,b), feature n=(h,d) -> (bh,t,d) fp16
          int t = m >> 2, b = m & 3, h = n >> 6, d = n & 63;
          ((_Float16*)outp)[(size_t)((b*NH + h)*TGT + t)*HD + d] = (_Float16)v;
        } else if constexpr (EPI == 1) { // V transposed: (bh,d,s) fp16
          int s = m >> 2, b = m & 3, h = n >> 6, d = n & 63;
          ((_Float16*)outp)[(size_t)((b*NH + h)*HD + d)*TGT + s] = (_Float16)v;
        } else {                         // f32 row-major (final output)
          ((float*)outp)[(size_t)m*EMB + n] = v;
        }
      }
}

// Flash attention per (bh, 64 t-rows): swapped QK^T (mfma(K,Q)) -> S[s][t] fragments,
// online softmax in exp2 units (scale folded into Q), PV via per-wave P LDS bounce.
// Emits O as split-bf16 in merged (token, e) layout + lse (log2 units).
__global__ __launch_bounds__(256) void flash_kernel(
    const _Float16* __restrict__ Qf, const _Float16* __restrict__ Kf,
    const _Float16* __restrict__ Vt, u16* __restrict__ Oh, u16* __restrict__ Ol,
    float* __restrict__ lse)
{
  __shared__ __align__(16) _Float16 Qs[64][72];
  __shared__ __align__(16) _Float16 Ks[64][72];
  __shared__ __align__(16) _Float16 Vs[64][72];      // [d][s]
  __shared__ __align__(16) _Float16 Ps[4][16][72];   // per-wave [t][s]
  const int tid = threadIdx.x, wave = tid >> 6, lane = tid & 63, lr = lane & 15, lg = lane >> 4;
  const int bh = blockIdx.y, t0 = blockIdx.x * 64;
  const int b = bh >> 4, h = bh & 15;

  #pragma unroll
  for (int i = 0; i < 2; i++) {
    int c = tid + i*256, r = c >> 3, co = (c & 7) * 8;
    *(uint4*)&Qs[r][co] = *(const uint4*)&Qf[((size_t)bh*TGT + t0 + r)*HD + co];
  }
  float m_run = -1e30f, l_run = 0.f;
  f32x4 zero = {0.f, 0.f, 0.f, 0.f};
  f32x4 accO[4];
  #pragma unroll
  for (int i = 0; i < 4; i++) accO[i] = zero;

  for (int s0 = 0; s0 < TGT; s0 += 64) {
    __syncthreads();
    #pragma unroll
    for (int i = 0; i < 2; i++) {
      int c = tid + i*256, r = c >> 3, co = (c & 7) * 8;
      *(uint4*)&Ks[r][co] = *(const uint4*)&Kf[((size_t)bh*TGT + s0 + r)*HD + co];
      *(uint4*)&Vs[r][co] = *(const uint4*)&Vt[((size_t)bh*HD + r)*TGT + s0 + co];
    }
    __syncthreads();
    f32x4 sacc[4];
    #pragma unroll
    for (int sf = 0; sf < 4; sf++) sacc[sf] = zero;
    #pragma unroll
    for (int sf = 0; sf < 4; sf++)
      #pragma unroll
      for (int kf = 0; kf < 2; kf++) {
        f16x8 a = *(const f16x8*)&Ks[sf*16 + lr][kf*32 + lg*8];
        f16x8 q = *(const f16x8*)&Qs[wave*16 + lr][kf*32 + lg*8];
        sacc[sf] = MFMA_F16(a, q, sacc[sf]);   // S[s=sf*16+lg*4+r][t=wave*16+lr]
      }
    float pm = -1e30f;
    #pragma unroll
    for (int sf = 0; sf < 4; sf++)
      #pragma unroll
      for (int r = 0; r < 4; r++) pm = fmaxf(pm, sacc[sf][r]);
    pm = fmaxf(pm, __shfl_xor(pm, 16, 64));
    pm = fmaxf(pm, __shfl_xor(pm, 32, 64));
    float m_new = fmaxf(m_run, pm);
    float fsc = exp2f(m_run - m_new);
    float psum = 0.f;
    #pragma unroll
    for (int sf = 0; sf < 4; sf++)
      #pragma unroll
      for (int r = 0; r < 4; r++) {
        float p = exp2f(sacc[sf][r] - m_new);
        sacc[sf][r] = p;
        psum += p;
      }
    psum += __shfl_xor(psum, 16, 64);
    psum += __shfl_xor(psum, 32, 64);
    l_run = l_run * fsc + psum;
    m_run = m_new;
    // P -> per-wave LDS (transposed to [t][s]); same-wave DS ordering makes this safe
    #pragma unroll
    for (int sf = 0; sf < 4; sf++) {
      f16x2 p01 = { (_Float16)sacc[sf][0], (_Float16)sacc[sf][1] };
      f16x2 p23 = { (_Float16)sacc[sf][2], (_Float16)sacc[sf][3] };
      *(f16x2*)&Ps[wave][lr][sf*16 + lg*4]     = p01;
      *(f16x2*)&Ps[wave][lr][sf*16 + lg*4 + 2] = p23;
    }
    float fr[4];
    #pragma unroll
    for (int r = 0; r < 4; r++) fr[r] = __shfl(fsc, lg*4 + r, 64);
    #pragma unroll
    for (int df = 0; df < 4; df++) {
      accO[df][0] *= fr[0]; accO[df][1] *= fr[1];
      accO[df][2] *= fr[2]; accO[df][3] *= fr[3];
    }
    f16x8 pa0 = *(const f16x8*)&Ps[wave][lr][lg*8];
    f16x8 pa1 = *(const f16x8*)&Ps[wave][lr][32 + lg*8];
    #pragma unroll
    for (int df = 0; df < 4; df++) {
      f16x8 v0 = *(const f16x8*)&Vs[df*16 + lr][lg*8];
      f16x8 v1 = *(const f16x8*)&Vs[df*16 + lr][32 + lg*8];
      accO[df] = MFMA_F16(pa0, v0, accO[df]);  // O[t=lg*4+r][d=df*16+lr]
      accO[df] = MFMA_F16(pa1, v1, accO[df]);
    }
  }
  float linv = 1.f / l_run;
  float rl[4];
  #pragma unroll
  for (int r = 0; r < 4; r++) rl[r] = __shfl(linv, lg*4 + r, 64);
  #pragma unroll
  for (int df = 0; df < 4; df++)
    #pragma unroll
    for (int r = 0; r < 4; r++) {
      float o = accO[df][r] * rl[r];
      int t = t0 + wave*16 + lg*4 + r;
      int d = df*16 + lr;
      size_t idx = (size_t)(t*BSZ + b)*EMB + h*HD + d;
      u16 hh, ll;
      split_one(o, hh, ll);
      Oh[idx] = hh; Ol[idx] = ll;
    }
  if (lane < 16)
    lse[(size_t)bh*TGT + t0 + wave*16 + lane] = m_run + log2f(l_run);
}

// avg_weights v2: one block per (b, 128t x 128s) tile; loop all 16 heads with
// global_load_lds staging (XOR-swizzled source so ds_read_b128 is conflict-free),
// accumulate p = exp2(S - lse) in registers, single direct global write.
__global__ __launch_bounds__(256) void avg_kernel(
    const _Float16* __restrict__ Qf, const _Float16* __restrict__ Kf,
    const float* __restrict__ lse, float* __restrict__ avgO)
{
  __shared__ __align__(16) _Float16 Qs[128][64];   // 16 KB, 128B rows, XOR-swizzled granules
  __shared__ __align__(16) _Float16 Ks[128][64];   // 16 KB
  __shared__ float lses[NH][128];                  // 8 KB
  const int tid = threadIdx.x, wave = tid >> 6, lane = tid & 63, lr = lane & 15, lg = lane >> 4;

  // XCD-chunked swizzle over 1024 blocks (1024 % 8 == 0 -> bijective)
  int fid = blockIdx.x;
  int nid = (fid & 7) * 128 + (fid >> 3);
  int st = nid & 15, tt = (nid >> 4) & 15, b = nid >> 8;
  int s0 = st * 128, t0 = tt * 128;

  // stage lse for all heads, this block's 128 t-rows
  #pragma unroll
  for (int i = 0; i < 8; i++) {
    int idx = tid + i * 256;               // 2048 = 16*128
    int hh = idx >> 7, t = idx & 127;
    lses[hh][t] = lse[(size_t)(b*NH + hh)*TGT + t0 + t];
  }

  f32x4 zero = {0.f, 0.f, 0.f, 0.f};
  f32x4 acc[2][8];
  #pragma unroll
  for (int i = 0; i < 2; i++)
    #pragma unroll
    for (int j = 0; j < 8; j++) acc[i][j] = zero;

  const int rQ = wave * 32;
  // per-lane source swizzle offset within a 1KB staging chunk:
  // LDS slot (row = J*8 + l>>3, granule = l&7) gets global granule (l&7)^(l>>3)
  const int srcsub = (((lane & 7) ^ (lane >> 3)) << 4) + (lane >> 3) * 128;

  for (int h = 0; h < NH; h++) {
    __syncthreads();   // protect LDS from previous head's readers
    {
      const char* qb = (const char*)(Qf + ((size_t)(b*NH + h)*TGT + t0) * HD);
      const char* kb = (const char*)(Kf + ((size_t)(b*NH + h)*TGT + s0) * HD);
      const char* gb = (wave < 2) ? qb : kb;
      char* lb = (char*)((wave < 2) ? &Qs[0][0] : &Ks[0][0]);
      const int half = (wave & 1) * 8;
      #pragma unroll
      for (int j = 0; j < 8; j++) {
        int J = half + j;
        GLOAD_LDS16(gb + (size_t)J * 1024 + srcsub, lb + J * 1024);
      }
    }
    __syncthreads();   // drains vmcnt -> staged data visible

    // hoist this head's lse values (one per output row this lane owns)
    float lsr[2][4];
    #pragma unroll
    for (int mf = 0; mf < 2; mf++)
      #pragma unroll
      for (int r = 0; r < 4; r++)
        lsr[mf][r] = lses[h][rQ + mf*16 + lg*4 + r];

    // Q fragments (swizzled read)
    f16x8 aq[2][2];
    #pragma unroll
    for (int mf = 0; mf < 2; mf++)
      #pragma unroll
      for (int kf = 0; kf < 2; kf++) {
        int row = rQ + mf*16 + lr;
        int cb = ((kf*4 + lg) ^ (row & 7)) << 4;
        aq[mf][kf] = *(const f16x8*)((const char*)&Qs[0][0] + row*128 + cb);
      }
    #pragma unroll
    for (int nf = 0; nf < 8; nf++) {
      f32x4 s4[2] = {zero, zero};
      #pragma unroll
      for (int kf = 0; kf < 2; kf++) {
        int row = nf*16 + lr;
        int cb = ((kf*4 + lg) ^ (row & 7)) << 4;
        f16x8 bk = *(const f16x8*)((const char*)&Ks[0][0] + row*128 + cb);
        s4[0] = MFMA_F16(aq[0][kf], bk, s4[0]);  // S[t=rQ+mf*16+lg*4+r][s=nf*16+lr]
        s4[1] = MFMA_F16(aq[1][kf], bk, s4[1]);
      }
      #pragma unroll
      for (int mf = 0; mf < 2; mf++)
        #pragma unroll
        for (int r = 0; r < 4; r++)
          acc[mf][nf][r] += exp2f(s4[mf][r] - lsr[mf][r]);
    }
  }

  // direct global write, /16
  #pragma unroll
  for (int mf = 0; mf < 2; mf++)
    #pragma unroll
    for (int nf = 0; nf < 8; nf++)
      #pragma unroll
      for (int r = 0; r < 4; r++) {
        int t = t0 + rQ + mf*16 + lg*4 + r;
        int s = s0 + nf*16 + lr;
        avgO[((size_t)b*TGT + t)*TGT + s] = acc[mf][nf][r] * (1.f/16.f);
      }
}

extern "C" void kernel_launch(void* const* d_in, const int* in_sizes, int n_in,
                              void* d_out, int out_size, void* d_ws, size_t ws_size,
                              hipStream_t stream) {
  const float* query = (const float*)d_in[0];
  const float* key_  = (const float*)d_in[1];
  const float* value = (const float*)d_in[2];
  const float* ipw   = (const float*)d_in[3];  // (3072,1024)
  const float* ipb   = (const float*)d_in[4];  // (3072,)
  const float* opw   = (const float*)d_in[5];  // (1024,1024)
  const float* opb   = (const float*)d_in[6];  // (1024,)
  float* out = (float*)d_out;
  float* avg = out + (size_t)TGT*BSZ*EMB;

  char* ws = (char*)d_ws;
  size_t o = 0;
  auto alloc = [&](size_t bytes) { char* p = ws + o; o += bytes; return p; };
  u16* Wh  = (u16*)alloc((size_t)3*EMB*EMB*2);
  u16* Wl  = (u16*)alloc((size_t)3*EMB*EMB*2);
  u16* Woh = (u16*)alloc((size_t)EMB*EMB*2);
  u16* Wol = (u16*)alloc((size_t)EMB*EMB*2);
  u16* Xh  = (u16*)alloc((size_t)NTOK*EMB*2);
  u16* Xl  = (u16*)alloc((size_t)NTOK*EMB*2);
  _Float16* Qf = (_Float16*)alloc((size_t)NTOK*EMB*2);
  _Float16* Kf = (_Float16*)alloc((size_t)NTOK*EMB*2);
  _Float16* Vt = (_Float16*)alloc((size_t)NTOK*EMB*2);
  u16* OhA = (u16*)alloc((size_t)NTOK*EMB*2);
  u16* OlA = (u16*)alloc((size_t)NTOK*EMB*2);
  float* lseA = (float*)alloc((size_t)BH*TGT*4);
  (void)ws_size; (void)in_sizes; (void)n_in; (void)out_size;
  // total ws use: ~128.5 MiB

  const float QSCALE = 0.18033688011112042f;  // log2(e)/8 -> exp2-unit scores

  split_kernel<<<3*EMB*EMB/1024, 256, 0, stream>>>(ipw, Wh, Wl, 3*EMB*EMB/4);
  split_kernel<<<EMB*EMB/1024, 256, 0, stream>>>(opw, Woh, Wol, EMB*EMB/4);

  dim3 ggrid(EMB/128, NTOK/128);
  split_kernel<<<NTOK*EMB/1024, 256, 0, stream>>>(query, Xh, Xl, NTOK*EMB/4);
  gemm_split<0><<<ggrid, 256, 0, stream>>>(Xh, Xl, Wh, Wl, ipb, QSCALE, (void*)Qf, EMB);
  split_kernel<<<NTOK*EMB/1024, 256, 0, stream>>>(key_, Xh, Xl, NTOK*EMB/4);
  gemm_split<0><<<ggrid, 256, 0, stream>>>(Xh, Xl, Wh + (size_t)EMB*EMB, Wl + (size_t)EMB*EMB,
                                           ipb + EMB, 1.0f, (void*)Kf, EMB);
  split_kernel<<<NTOK*EMB/1024, 256, 0, stream>>>(value, Xh, Xl, NTOK*EMB/4);
  gemm_split<1><<<ggrid, 256, 0, stream>>>(Xh, Xl, Wh + (size_t)2*EMB*EMB, Wl + (size_t)2*EMB*EMB,
                                           ipb + 2*EMB, 1.0f, (void*)Vt, EMB);

  flash_kernel<<<dim3(TGT/64, BH), 256, 0, stream>>>(Qf, Kf, Vt, OhA, OlA, lseA);
  avg_kernel<<<1024, 256, 0, stream>>>(Qf, Kf, lseA, avg);
  gemm_split<2><<<ggrid, 256, 0, stream>>>(OhA, OlA, Woh, Wol, opb, 1.0f, (void*)out, EMB);
}

// Round 6
// 666.318 us; speedup vs baseline: 1.7017x; 1.0715x over previous
//
#include <hip/hip_runtime.h>
#include <hip/hip_bf16.h>
#include <hip/hip_fp16.h>

#define TGT 2048
#define BSZ 4
#define EMB 1024
#define NH  16
#define HD  64
#define NTOK (TGT*BSZ)   // 8192
#define BH   (BSZ*NH)    // 64

typedef unsigned short u16;
typedef __attribute__((ext_vector_type(8)))  short        s16x8;
typedef __attribute__((ext_vector_type(8)))  _Float16     f16x8;
typedef __attribute__((ext_vector_type(2)))  _Float16     f16x2;
typedef __attribute__((ext_vector_type(2)))  __fp16       fp16x2;   // cvt_pkrtz return type
typedef __attribute__((ext_vector_type(4)))  float        f32x4;
typedef __attribute__((ext_vector_type(16))) float        f32x16;
typedef __attribute__((ext_vector_type(4)))  unsigned int u32x4;

#define MFMA_BF16(a,b,c)  __builtin_amdgcn_mfma_f32_16x16x32_bf16(a,b,c,0,0,0)
#define MFMA_F16(a,b,c)   __builtin_amdgcn_mfma_f32_16x16x32_f16(a,b,c,0,0,0)
#define MFMA32_F16(a,b,c) __builtin_amdgcn_mfma_f32_32x32x16_f16(a,b,c,0,0,0)

// async global->LDS, 16B per lane; LDS dest = wave-uniform base + lane*16
#define GLOAD_LDS16(gsrc, ldst) \
  __builtin_amdgcn_global_load_lds((const __attribute__((address_space(1))) unsigned int*)(gsrc), \
                                   (__attribute__((address_space(3))) unsigned int*)(ldst), 16, 0, 0)

__device__ __forceinline__ void split_one(float x, u16& h, u16& l) {
  __hip_bfloat16 hb = __float2bfloat16(x);
  float hf = __bfloat162float(hb);
  __hip_bfloat16 lb = __float2bfloat16(x - hf);   // exact remainder, then rounded
  h = *reinterpret_cast<u16*>(&hb);
  l = *reinterpret_cast<u16*>(&lb);
}

// f32 -> (bf16 hi, bf16 lo), vectorized x4
__global__ __launch_bounds__(256) void split_kernel(const float* __restrict__ x,
    u16* __restrict__ hi, u16* __restrict__ lo, int n4) {
  int i = blockIdx.x * 256 + threadIdx.x;
  if (i >= n4) return;
  float4 v = reinterpret_cast<const float4*>(x)[i];
  ushort4 h, l;
  split_one(v.x, h.x, l.x);
  split_one(v.y, h.y, l.y);
  split_one(v.z, h.z, l.z);
  split_one(v.w, h.w, l.w);
  reinterpret_cast<ushort4*>(hi)[i] = h;
  reinterpret_cast<ushort4*>(lo)[i] = l;
}

// Split-bf16 NT GEMM v2 (m97-style): C[m][n] = sum_k (Ah+Al)[m][k]*(Bh+Bl)[n][k],
// 3-product Markidis. BM=BN=128, BK=32, 4 waves (each 32m x 128n, acc 2x8 f32x4).
// LDS tiles [128 rows][128B]: granules g0-3 = hi k-halves, g4-7 = lo; stored granule
// XOR-swizzled by (row&7) so ds_read_b128 fragment reads are conflict-free.
// Staged via global_load_lds w=16 with pre-swizzled per-lane SOURCE (m173 pattern).
// EPI: 0 = fp16 scatter (bh,t,d) with scale; 1 = fp16 scatter transposed (bh,d,s); 2 = f32 row-major.
template<int EPI>
__global__ __launch_bounds__(256) void gemm_split(
    const u16* __restrict__ Ah, const u16* __restrict__ Al,
    const u16* __restrict__ Bh, const u16* __restrict__ Bl,
    const float* __restrict__ bias, float scale, void* __restrict__ outp, int K)
{
  __shared__ __align__(16) u16 As[128*64];   // 16 KB
  __shared__ __align__(16) u16 Bs[128*64];   // 16 KB
  const int tid  = threadIdx.x;
  const int bm0  = blockIdx.y * 128;
  const int bn0  = blockIdx.x * 128;
  const int wave = tid >> 6, lane = tid & 63, lr = lane & 15, lg = lane >> 4;

  f32x4 zero = {0.f, 0.f, 0.f, 0.f};
  f32x4 acc[2][8];
  #pragma unroll
  for (int i = 0; i < 2; i++)
    #pragma unroll
    for (int j = 0; j < 8; j++) acc[i][j] = zero;

  const u16* srcA[4];
  const u16* srcB[4];
  #pragma unroll
  for (int j = 0; j < 4; j++) {
    int gi  = tid + j*256;
    int row = gi >> 3;
    int lgc = (gi & 7) ^ (row & 7);
    const u16* baA = (lgc < 4) ? Ah : Al;
    const u16* baB = (lgc < 4) ? Bh : Bl;
    srcA[j] = baA + (size_t)(bm0 + row)*K + (lgc & 3)*8;
    srcB[j] = baB + (size_t)(bn0 + row)*K + (lgc & 3)*8;
  }
  char* AsB = (char*)As;
  char* BsB = (char*)Bs;
  const int ldsb = wave*1024;   // wave-uniform chunk base

  for (int kt = 0; kt < K; kt += 32) {
    __syncthreads();
    #pragma unroll
    for (int j = 0; j < 4; j++) {
      GLOAD_LDS16(srcA[j] + kt, AsB + ldsb + j*4096);
      GLOAD_LDS16(srcB[j] + kt, BsB + ldsb + j*4096);
    }
    __syncthreads();   // drains vmcnt -> staged tiles visible

    s16x8 ah[2], al2[2];
    #pragma unroll
    for (int mf = 0; mf < 2; mf++) {
      int row = wave*32 + mf*16 + lr;
      const char* rb = AsB + row*128;
      ah[mf]  = *(const s16x8*)(rb + (((lg    ) ^ (row & 7)) << 4));
      al2[mf] = *(const s16x8*)(rb + (((lg | 4) ^ (row & 7)) << 4));
    }
    #pragma unroll
    for (int nf = 0; nf < 8; nf++) {
      int row = nf*16 + lr;
      const char* rb = BsB + row*128;
      s16x8 bh8 = *(const s16x8*)(rb + (((lg    ) ^ (row & 7)) << 4));
      s16x8 bl8 = *(const s16x8*)(rb + (((lg | 4) ^ (row & 7)) << 4));
      #pragma unroll
      for (int mf = 0; mf < 2; mf++) {
        acc[mf][nf] = MFMA_BF16(al2[mf], bh8, acc[mf][nf]);
        acc[mf][nf] = MFMA_BF16(ah[mf],  bl8, acc[mf][nf]);
        acc[mf][nf] = MFMA_BF16(ah[mf],  bh8, acc[mf][nf]);
      }
    }
  }
  // Epilogue. D layout (verified m89/m91): col = lane&15, row = (lane>>4)*4 + reg.
  #pragma unroll
  for (int mf = 0; mf < 2; mf++)
    #pragma unroll
    for (int nf = 0; nf < 8; nf++)
      #pragma unroll
      for (int r = 0; r < 4; r++) {
        int m = bm0 + wave*32 + mf*16 + lg*4 + r;
        int n = bn0 + nf*16 + lr;
        float v = (acc[mf][nf][r] + bias[n]) * scale;
        if constexpr (EPI == 0) {        // token m=(t,b), feature n=(h,d) -> (bh,t,d) fp16
          int t = m >> 2, b = m & 3, h = n >> 6, d = n & 63;
          ((_Float16*)outp)[(size_t)((b*NH + h)*TGT + t)*HD + d] = (_Float16)v;
        } else if constexpr (EPI == 1) { // V transposed: (bh,d,s) fp16
          int s = m >> 2, b = m & 3, h = n >> 6, d = n & 63;
          ((_Float16*)outp)[(size_t)((b*NH + h)*HD + d)*TGT + s] = (_Float16)v;
        } else {                         // f32 row-major (final output)
          ((float*)outp)[(size_t)m*EMB + n] = v;
        }
      }
}

// Flash v2: 4 waves x 32 t-rows = 128 t/block, KVBLK=64, 32x32x16 MFMAs.
// Swapped QK^T -> S[s][t] (lane owns ONE t); PV as O^T = mfma(V, P) keeps
// col = t, so all softmax scalars stay per-lane (no broadcast shuffles).
// P redistribution S-frag -> PV A-frag via cvt_pkrtz + v_permlane32_swap_b32
// (no LDS bounce). K/V staged with global_load_lds w=16, XOR-swizzled source.
__global__ __launch_bounds__(256) void flash_kernel(
    const _Float16* __restrict__ Qf, const _Float16* __restrict__ Kf,
    const _Float16* __restrict__ Vt, u16* __restrict__ Oh, u16* __restrict__ Ol,
    float* __restrict__ lse)
{
  __shared__ __align__(16) _Float16 Ks[64*64];  // [s][d] 128B rows, swizzled
  __shared__ __align__(16) _Float16 Vs[64*64];  // [d][s] 128B rows, swizzled
  const int tid = threadIdx.x, wq = tid >> 6, lane = tid & 63;
  const int lt = lane & 31, hl = lane >> 5;
  const int bh = blockIdx.y, t0 = blockIdx.x * 128;
  const int b = bh >> 4, h = bh & 15;
  const int t = t0 + wq*32 + lt;        // this lane's t-row

  // Q fragments from global (once): qf[kk] holds d = 16kk + 8hl + j, j=0..7
  f16x8 qf[4];
  #pragma unroll
  for (int kk = 0; kk < 4; kk++)
    qf[kk] = *(const f16x8*)&Qf[((size_t)bh*TGT + t)*HD + kk*16 + hl*8];

  float m_run = -1e30f, l_run = 0.f;
  f32x16 accO[2];   // O^T: d = 32df + (r&3)+8*(r>>2)+4hl, col t
  #pragma unroll
  for (int i = 0; i < 16; i++) { accO[0][i] = 0.f; accO[1][i] = 0.f; }

  char* KsB = (char*)Ks;
  char* VsB = (char*)Vs;

  for (int s0 = 0; s0 < TGT; s0 += 64) {
    __syncthreads();
    #pragma unroll
    for (int j = 0; j < 2; j++) {
      int gi = tid + j*256;                       // granule 0..511
      int row = gi >> 3, sg = (gi & 7) ^ (row & 7);
      GLOAD_LDS16(Kf + ((size_t)bh*TGT + s0 + row)*HD + sg*8, KsB + wq*1024 + j*4096);
      GLOAD_LDS16(Vt + ((size_t)bh*HD + row)*TGT + s0 + sg*8, VsB + wq*1024 + j*4096);
    }
    __syncthreads();   // drains vmcnt

    // QK^T: sacc[sf] = S[s = 32sf + (r&3)+8(r>>2)+4hl][t]
    f32x16 sacc[2];
    #pragma unroll
    for (int i = 0; i < 16; i++) { sacc[0][i] = 0.f; sacc[1][i] = 0.f; }
    #pragma unroll
    for (int sf = 0; sf < 2; sf++)
      #pragma unroll
      for (int kk = 0; kk < 4; kk++) {
        int row = sf*32 + lt;
        int g = (2*kk + hl) ^ (row & 7);
        f16x8 kfr = *(const f16x8*)(KsB + row*128 + g*16);
        sacc[sf] = MFMA32_F16(kfr, qf[kk], sacc[sf]);
      }

    // online softmax — all per-lane scalars (lane owns one t)
    float pm = -1e30f;
    #pragma unroll
    for (int sf = 0; sf < 2; sf++)
      #pragma unroll
      for (int r = 0; r < 16; r++) pm = fmaxf(pm, sacc[sf][r]);
    pm = fmaxf(pm, __shfl_xor(pm, 32, 64));
    float m_new = fmaxf(m_run, pm);
    float fsc = exp2f(m_run - m_new);
    float psum = 0.f;
    #pragma unroll
    for (int sf = 0; sf < 2; sf++)
      #pragma unroll
      for (int r = 0; r < 16; r++) {
        float p = exp2f(sacc[sf][r] - m_new);
        sacc[sf][r] = p;
        psum += p;
      }
    psum += __shfl_xor(psum, 32, 64);
    l_run = l_run * fsc + psum;
    m_run = m_new;
    accO[0] *= fsc;
    accO[1] *= fsc;

    // P (f32 S-frag) -> fp16 PV A-frags via pack + permlane32_swap; then PV
    #pragma unroll
    for (int sf = 0; sf < 2; sf++) {
      unsigned int P0[4], P1[4];
      #pragma unroll
      for (int q = 0; q < 4; q++) {
        union { fp16x2 h2; unsigned int u; } c0, c1;
        c0.h2 = __builtin_amdgcn_cvt_pkrtz(sacc[sf][4*q],     sacc[sf][4*q + 1]);
        c1.h2 = __builtin_amdgcn_cvt_pkrtz(sacc[sf][4*q + 2], sacc[sf][4*q + 3]);
        P0[q] = c0.u;
        P1[q] = c1.u;
      }
      #pragma unroll
      for (int mp = 0; mp < 2; mp++) {
        unsigned int a0 = P0[2*mp], b0 = P0[2*mp + 1];
        unsigned int a1 = P1[2*mp], b1 = P1[2*mp + 1];
        asm("v_permlane32_swap_b32 %0, %1" : "+v"(a0), "+v"(b0));
        asm("v_permlane32_swap_b32 %0, %1" : "+v"(a1), "+v"(b1));
        union { u32x4 u; f16x8 f; } pw;
        pw.u = (u32x4){a0, a1, b0, b1};   // k = s = 16m + 8hl + j, j=0..7
        const int m = sf*2 + mp;
        #pragma unroll
        for (int df = 0; df < 2; df++) {
          int row = df*32 + lt;
          int g = (2*m + hl) ^ (row & 7);
          f16x8 vfr = *(const f16x8*)(VsB + row*128 + g*16);
          accO[df] = MFMA32_F16(vfr, pw.f, accO[df]);   // O^T[d][t]
        }
      }
    }
  }

  // epilogue: O row (64 d) per lane, split-bf16, ushort4 stores
  float linv = 1.f / l_run;
  #pragma unroll
  for (int df = 0; df < 2; df++)
    #pragma unroll
    for (int q = 0; q < 4; q++) {
      ushort4 hs, ls;
      float o0 = accO[df][4*q]     * linv;
      float o1 = accO[df][4*q + 1] * linv;
      float o2 = accO[df][4*q + 2] * linv;
      float o3 = accO[df][4*q + 3] * linv;
      split_one(o0, hs.x, ls.x);
      split_one(o1, hs.y, ls.y);
      split_one(o2, hs.z, ls.z);
      split_one(o3, hs.w, ls.w);
      int d0 = 32*df + 8*q + 4*hl;
      size_t idx = ((size_t)t*BSZ + b)*EMB + h*HD + d0;
      *(ushort4*)&Oh[idx] = hs;
      *(ushort4*)&Ol[idx] = ls;
    }
  if (hl == 0)
    lse[(size_t)bh*TGT + t] = m_run + log2f(l_run);
}

// avg_weights: one block per (b, 128t x 128s) tile; loop all 16 heads with
// global_load_lds staging (XOR-swizzled source so ds_read_b128 is conflict-free),
// accumulate p = exp2(S - lse) in registers, single direct global write.
__global__ __launch_bounds__(256) void avg_kernel(
    const _Float16* __restrict__ Qf, const _Float16* __restrict__ Kf,
    const float* __restrict__ lse, float* __restrict__ avgO)
{
  __shared__ __align__(16) _Float16 Qs[128][64];   // 16 KB, 128B rows, XOR-swizzled granules
  __shared__ __align__(16) _Float16 Ks[128][64];   // 16 KB
  __shared__ float lses[NH][128];                  // 8 KB
  const int tid = threadIdx.x, wave = tid >> 6, lane = tid & 63, lr = lane & 15, lg = lane >> 4;

  // XCD-chunked swizzle over 1024 blocks (1024 % 8 == 0 -> bijective)
  int fid = blockIdx.x;
  int nid = (fid & 7) * 128 + (fid >> 3);
  int st = nid & 15, tt = (nid >> 4) & 15, b = nid >> 8;
  int s0 = st * 128, t0 = tt * 128;

  #pragma unroll
  for (int i = 0; i < 8; i++) {
    int idx = tid + i * 256;               // 2048 = 16*128
    int hh = idx >> 7, t = idx & 127;
    lses[hh][t] = lse[(size_t)(b*NH + hh)*TGT + t0 + t];
  }

  f32x4 zero = {0.f, 0.f, 0.f, 0.f};
  f32x4 acc[2][8];
  #pragma unroll
  for (int i = 0; i < 2; i++)
    #pragma unroll
    for (int j = 0; j < 8; j++) acc[i][j] = zero;

  const int rQ = wave * 32;
  const int srcsub = (((lane & 7) ^ (lane >> 3)) << 4) + (lane >> 3) * 128;

  for (int h = 0; h < NH; h++) {
    __syncthreads();
    {
      const char* qb = (const char*)(Qf + ((size_t)(b*NH + h)*TGT + t0) * HD);
      const char* kb = (const char*)(Kf + ((size_t)(b*NH + h)*TGT + s0) * HD);
      const char* gb = (wave < 2) ? qb : kb;
      char* lb = (char*)((wave < 2) ? &Qs[0][0] : &Ks[0][0]);
      const int half = (wave & 1) * 8;
      #pragma unroll
      for (int j = 0; j < 8; j++) {
        int J = half + j;
        GLOAD_LDS16(gb + (size_t)J * 1024 + srcsub, lb + J * 1024);
      }
    }
    __syncthreads();

    float lsr[2][4];
    #pragma unroll
    for (int mf = 0; mf < 2; mf++)
      #pragma unroll
      for (int r = 0; r < 4; r++)
        lsr[mf][r] = lses[h][rQ + mf*16 + lg*4 + r];

    f16x8 aq[2][2];
    #pragma unroll
    for (int mf = 0; mf < 2; mf++)
      #pragma unroll
      for (int kf = 0; kf < 2; kf++) {
        int row = rQ + mf*16 + lr;
        int cb = ((kf*4 + lg) ^ (row & 7)) << 4;
        aq[mf][kf] = *(const f16x8*)((const char*)&Qs[0][0] + row*128 + cb);
      }
    #pragma unroll
    for (int nf = 0; nf < 8; nf++) {
      f32x4 s4[2] = {zero, zero};
      #pragma unroll
      for (int kf = 0; kf < 2; kf++) {
        int row = nf*16 + lr;
        int cb = ((kf*4 + lg) ^ (row & 7)) << 4;
        f16x8 bk = *(const f16x8*)((const char*)&Ks[0][0] + row*128 + cb);
        s4[0] = MFMA_F16(aq[0][kf], bk, s4[0]);
        s4[1] = MFMA_F16(aq[1][kf], bk, s4[1]);
      }
      #pragma unroll
      for (int mf = 0; mf < 2; mf++)
        #pragma unroll
        for (int r = 0; r < 4; r++)
          acc[mf][nf][r] += exp2f(s4[mf][r] - lsr[mf][r]);
    }
  }

  #pragma unroll
  for (int mf = 0; mf < 2; mf++)
    #pragma unroll
    for (int nf = 0; nf < 8; nf++)
      #pragma unroll
      for (int r = 0; r < 4; r++) {
        int ti = t0 + rQ + mf*16 + lg*4 + r;
        int sj = s0 + nf*16 + lr;
        avgO[((size_t)b*TGT + ti)*TGT + sj] = acc[mf][nf][r] * (1.f/16.f);
      }
}

extern "C" void kernel_launch(void* const* d_in, const int* in_sizes, int n_in,
                              void* d_out, int out_size, void* d_ws, size_t ws_size,
                              hipStream_t stream) {
  const float* query = (const float*)d_in[0];
  const float* key_  = (const float*)d_in[1];
  const float* value = (const float*)d_in[2];
  const float* ipw   = (const float*)d_in[3];  // (3072,1024)
  const float* ipb   = (const float*)d_in[4];  // (3072,)
  const float* opw   = (const float*)d_in[5];  // (1024,1024)
  const float* opb   = (const float*)d_in[6];  // (1024,)
  float* out = (float*)d_out;
  float* avg = out + (size_t)TGT*BSZ*EMB;

  char* ws = (char*)d_ws;
  size_t o = 0;
  auto alloc = [&](size_t bytes) { char* p = ws + o; o += bytes; return p; };
  u16* Wh  = (u16*)alloc((size_t)3*EMB*EMB*2);
  u16* Wl  = (u16*)alloc((size_t)3*EMB*EMB*2);
  u16* Woh = (u16*)alloc((size_t)EMB*EMB*2);
  u16* Wol = (u16*)alloc((size_t)EMB*EMB*2);
  u16* Xh  = (u16*)alloc((size_t)NTOK*EMB*2);
  u16* Xl  = (u16*)alloc((size_t)NTOK*EMB*2);
  _Float16* Qf = (_Float16*)alloc((size_t)NTOK*EMB*2);
  _Float16* Kf = (_Float16*)alloc((size_t)NTOK*EMB*2);
  _Float16* Vt = (_Float16*)alloc((size_t)NTOK*EMB*2);
  u16* OhA = (u16*)alloc((size_t)NTOK*EMB*2);
  u16* OlA = (u16*)alloc((size_t)NTOK*EMB*2);
  float* lseA = (float*)alloc((size_t)BH*TGT*4);
  (void)ws_size; (void)in_sizes; (void)n_in; (void)out_size;
  // total ws use: ~128.5 MiB

  const float QSCALE = 0.18033688011112042f;  // log2(e)/8 -> exp2-unit scores

  split_kernel<<<3*EMB*EMB/1024, 256, 0, stream>>>(ipw, Wh, Wl, 3*EMB*EMB/4);
  split_kernel<<<EMB*EMB/1024, 256, 0, stream>>>(opw, Woh, Wol, EMB*EMB/4);

  dim3 ggrid(EMB/128, NTOK/128);
  split_kernel<<<NTOK*EMB/1024, 256, 0, stream>>>(query, Xh, Xl, NTOK*EMB/4);
  gemm_split<0><<<ggrid, 256, 0, stream>>>(Xh, Xl, Wh, Wl, ipb, QSCALE, (void*)Qf, EMB);
  split_kernel<<<NTOK*EMB/1024, 256, 0, stream>>>(key_, Xh, Xl, NTOK*EMB/4);
  gemm_split<0><<<ggrid, 256, 0, stream>>>(Xh, Xl, Wh + (size_t)EMB*EMB, Wl + (size_t)EMB*EMB,
                                           ipb + EMB, 1.0f, (void*)Kf, EMB);
  split_kernel<<<NTOK*EMB/1024, 256, 0, stream>>>(value, Xh, Xl, NTOK*EMB/4);
  gemm_split<1><<<ggrid, 256, 0, stream>>>(Xh, Xl, Wh + (size_t)2*EMB*EMB, Wl + (size_t)2*EMB*EMB,
                                           ipb + 2*EMB, 1.0f, (void*)Vt, EMB);

  flash_kernel<<<dim3(TGT/128, BH), 256, 0, stream>>>(Qf, Kf, Vt, OhA, OlA, lseA);
  avg_kernel<<<1024, 256, 0, stream>>>(Qf, Kf, lseA, avg);
  gemm_split<2><<<ggrid, 256, 0, stream>>>(OhA, OlA, Woh, Wol, opb, 1.0f, (void*)out, EMB);
}